// Round 4
// baseline (3219.283 us; speedup 1.0000x reference)
//
#include <hip/hip_runtime.h>
#include <stdint.h>

#define TT 512
#define BB 64
#define DD 1024
#define HH 1024

typedef float  f32x4   __attribute__((ext_vector_type(4)));
typedef float  float4v __attribute__((ext_vector_type(4)));
typedef short  bf16x8  __attribute__((ext_vector_type(8)));
typedef short  short4v __attribute__((ext_vector_type(4)));
typedef unsigned long long u64;

__device__ __forceinline__ short f2bf(float x) {
  uint32_t u = __builtin_bit_cast(uint32_t, x);
  u += 0x7fffu + ((u >> 16) & 1u);   // RNE to bf16
  return (short)(u >> 16);
}
__device__ __forceinline__ float bf2f(short s) {
  uint32_t u = ((uint32_t)(uint16_t)s) << 16;
  return __builtin_bit_cast(float, u);
}

// MALL-coherent (agent-scope, L1/L2-bypassing) accesses — no cache flushes.
__device__ __forceinline__ u64 aload(const u64* p) {
  return __hip_atomic_load(p, __ATOMIC_RELAXED, __HIP_MEMORY_SCOPE_AGENT);
}
__device__ __forceinline__ void astore(u64* p, u64 v) {
  __hip_atomic_store(p, v, __ATOMIC_RELAXED, __HIP_MEMORY_SCOPE_AGENT);
}

union HU { u64 q[2]; bf16x8 v; };

// ---------------- W transpose + hi/lo split: W[k][n] f32 -> Wt_hi/lo[n][k] bf16 ----
__global__ __launch_bounds__(256) void k_wsplit(
    const float* __restrict__ Wih, const float* __restrict__ Whh,
    short* __restrict__ ih_hi, short* __restrict__ ih_lo,
    short* __restrict__ hh_hi, short* __restrict__ hh_lo)
{
  __shared__ float tile[64][65];
  int bid = blockIdx.x;
  int z = bid >> 8;              // 0: W_ih, 1: W_hh
  int tt = bid & 255;
  int tk = tt >> 4, tn = tt & 15;
  const float* __restrict__ src = z ? Whh : Wih;
  short* __restrict__ dhi = z ? hh_hi : ih_hi;
  short* __restrict__ dlo = z ? hh_lo : ih_lo;
  int k0 = tk * 64, n0 = tn * 64;
  int tid = threadIdx.x;
  #pragma unroll
  for (int i = 0; i < 4; ++i) {
    int idx = tid + i * 256;
    int r = idx >> 4, c4 = (idx & 15) * 4;
    float4v v = *reinterpret_cast<const float4v*>(&src[(size_t)(k0 + r) * HH + n0 + c4]);
    tile[r][c4 + 0] = v[0]; tile[r][c4 + 1] = v[1];
    tile[r][c4 + 2] = v[2]; tile[r][c4 + 3] = v[3];
  }
  __syncthreads();
  #pragma unroll
  for (int i = 0; i < 4; ++i) {
    int idx = tid + i * 256;
    int n = idx >> 4, kq = (idx & 15) * 4;
    short4v vh, vl;
    #pragma unroll
    for (int j = 0; j < 4; ++j) {
      float x = tile[kq + j][n];
      short h = f2bf(x);
      vh[j] = h;
      vl[j] = f2bf(x - bf2f(h));
    }
    *reinterpret_cast<short4v*>(&dhi[(size_t)(n0 + n) * 1024 + k0 + kq]) = vh;
    *reinterpret_cast<short4v*>(&dlo[(size_t)(n0 + n) * 1024 + k0 + kq]) = vl;
  }
}

// ---------------- x_proj GEMM: [32768 x 1024] = input @ W_ih + bias --------------
__global__ __launch_bounds__(256, 2) void k_gemm_xp(
    const float* __restrict__ A, const short* __restrict__ Bt_hi,
    const short* __restrict__ Bt_lo, const float* __restrict__ bias,
    float* __restrict__ xp)
{
  __shared__ __align__(16) short Ah[4096];
  __shared__ __align__(16) short Al[4096];
  __shared__ __align__(16) short Bh[4096];
  __shared__ __align__(16) short Bl[4096];
  int bid = blockIdx.x;
  int mb = bid & 255, nb = bid >> 8;
  size_t m0 = (size_t)mb * 128;
  int n0 = nb * 128;
  int tid = threadIdx.x;
  int lane = tid & 63, wid = tid >> 6;
  int wm = wid >> 1, wn = wid & 1;
  int lr = lane & 15, lk = lane >> 4;

  f32x4 acc[4][4];
  #pragma unroll
  for (int mt = 0; mt < 4; ++mt)
    #pragma unroll
    for (int nt = 0; nt < 4; ++nt) {
      acc[mt][nt][0] = 0.f; acc[mt][nt][1] = 0.f;
      acc[mt][nt][2] = 0.f; acc[mt][nt][3] = 0.f;
    }

  for (int kt = 0; kt < 32; ++kt) {
    int k0 = kt * 32;
    __syncthreads();
    #pragma unroll
    for (int i = 0; i < 4; ++i) {
      int idx = tid + i * 256;
      int r = idx >> 3, q = idx & 7;
      float4v v = *reinterpret_cast<const float4v*>(&A[(m0 + r) * 1024 + k0 + q * 4]);
      short4v vh, vl;
      #pragma unroll
      for (int j = 0; j < 4; ++j) {
        short h = f2bf(v[j]);
        vh[j] = h;
        vl[j] = f2bf(v[j] - bf2f(h));
      }
      int off = ((q >> 1) * 128 + r) * 8 + (q & 1) * 4;
      *reinterpret_cast<short4v*>(&Ah[off]) = vh;
      *reinterpret_cast<short4v*>(&Al[off]) = vl;
    }
    {
      int n = tid >> 1, half = tid & 1;
      size_t gb = (size_t)(n0 + n) * 1024 + k0 + half * 16;
      bf16x8 h0 = *reinterpret_cast<const bf16x8*>(&Bt_hi[gb]);
      bf16x8 h1 = *reinterpret_cast<const bf16x8*>(&Bt_hi[gb + 8]);
      bf16x8 l0 = *reinterpret_cast<const bf16x8*>(&Bt_lo[gb]);
      bf16x8 l1 = *reinterpret_cast<const bf16x8*>(&Bt_lo[gb + 8]);
      int kb = half * 2;
      *reinterpret_cast<bf16x8*>(&Bh[(kb * 128 + n) * 8]) = h0;
      *reinterpret_cast<bf16x8*>(&Bh[((kb + 1) * 128 + n) * 8]) = h1;
      *reinterpret_cast<bf16x8*>(&Bl[(kb * 128 + n) * 8]) = l0;
      *reinterpret_cast<bf16x8*>(&Bl[((kb + 1) * 128 + n) * 8]) = l1;
    }
    __syncthreads();

    bf16x8 a_h[4], a_l[4], b_h[4], b_l[4];
    #pragma unroll
    for (int mt = 0; mt < 4; ++mt) {
      int off = (lk * 128 + wm * 64 + mt * 16 + lr) * 8;
      a_h[mt] = *reinterpret_cast<const bf16x8*>(&Ah[off]);
      a_l[mt] = *reinterpret_cast<const bf16x8*>(&Al[off]);
    }
    #pragma unroll
    for (int nt = 0; nt < 4; ++nt) {
      int off = (lk * 128 + wn * 64 + nt * 16 + lr) * 8;
      b_h[nt] = *reinterpret_cast<const bf16x8*>(&Bh[off]);
      b_l[nt] = *reinterpret_cast<const bf16x8*>(&Bl[off]);
    }
    #pragma unroll
    for (int mt = 0; mt < 4; ++mt)
      #pragma unroll
      for (int nt = 0; nt < 4; ++nt) {
        acc[mt][nt] = __builtin_amdgcn_mfma_f32_16x16x32_bf16(a_h[mt], b_h[nt], acc[mt][nt], 0, 0, 0);
        acc[mt][nt] = __builtin_amdgcn_mfma_f32_16x16x32_bf16(a_h[mt], b_l[nt], acc[mt][nt], 0, 0, 0);
        acc[mt][nt] = __builtin_amdgcn_mfma_f32_16x16x32_bf16(a_l[mt], b_h[nt], acc[mt][nt], 0, 0, 0);
      }
  }
  #pragma unroll
  for (int nt = 0; nt < 4; ++nt) {
    int col = n0 + wn * 64 + nt * 16 + lr;
    float bv = bias[col];
    #pragma unroll
    for (int mt = 0; mt < 4; ++mt)
      #pragma unroll
      for (int r = 0; r < 4; ++r) {
        size_t row = m0 + wm * 64 + mt * 16 + lk * 4 + r;
        xp[row * 1024 + col] = acc[mt][nt][r] + bv;
      }
  }
}

// ---------------- pack init_state into h plane layout [g][kb128][row16][8] --------
__global__ __launch_bounds__(256) void k_init_h(
    const float* __restrict__ init, short* __restrict__ hhi, short* __restrict__ hlo)
{
  int i = blockIdx.x * 256 + threadIdx.x;   // 0..65535
  float v = init[i];
  int b = i >> 10, n = i & 1023;
  int g = b >> 4, row = b & 15, kb = n >> 3, e = n & 7;
  size_t off = ((size_t)(g * 128 + kb) * 16 + row) * 8 + e;
  short h = f2bf(v);
  hhi[off] = h;
  hlo[off] = f2bf(v - bf2f(h));
}

// ---------------- persistent recurrence: 512 steps, 4 groups x 32 WGs ------------
// Register-resident W; wave=K-quarter; per-wave fire-and-forget flags;
// single polling wave per WG (wave 3) + barrier release; reduce split on 2 waves.
__global__ __launch_bounds__(256, 1) void k_rnn(
    const float* __restrict__ xp,
    const short* __restrict__ whh_hi, const short* __restrict__ whh_lo,
    u64* __restrict__ hhi64, u64* __restrict__ hlo64,
    unsigned* __restrict__ flags, float* __restrict__ out)
{
  __shared__ __align__(16) short Wh[32768];   // one-time staging only
  __shared__ __align__(16) short Wl[32768];
  __shared__ __align__(16) float red[4 * 2 * 64 * 4];  // [kh][nt][lane][4]
  __shared__ __align__(16) float stage[512];           // [row16][col32]

  int bid = blockIdx.x;
  int g = bid & 3;               // batch-row group: rows g*16..+16
  int w = bid >> 2;              // 0..31: column slice
  int c0 = w * 32;
  int tid = threadIdx.x;
  int lane = tid & 63;
  int kh = tid >> 6;             // wave = K-quarter (8 ksteps)
  int lr = lane & 15, lk = lane >> 4;

  // one-time: stage W slice fragment-major into LDS
  {
    int combo = tid >> 1, ksh = tid & 1;
    int colw = combo >> 2, lkf = combo & 3;
    int ntf = colw >> 4, lrf = colw & 15;
    #pragma unroll
    for (int j = 0; j < 16; ++j) {
      int kstep = ksh * 16 + j;
      int dst = ((ntf * 32 + kstep) * 64 + lrf * 4 + lkf) * 8;
      size_t src = (size_t)(c0 + colw) * 1024 + kstep * 32 + lkf * 8;
      *reinterpret_cast<bf16x8*>(&Wh[dst]) = *reinterpret_cast<const bf16x8*>(&whh_hi[src]);
      *reinterpret_cast<bf16x8*>(&Wl[dst]) = *reinterpret_cast<const bf16x8*>(&whh_lo[src]);
    }
  }
  __syncthreads();
  // one-time: wave's K-quarter of W (both N-tiles) into registers
  bf16x8 w_h[8][2], w_l[8][2];
  #pragma unroll
  for (int ks = 0; ks < 8; ++ks) {
    int kstep = kh * 8 + ks;
    #pragma unroll
    for (int nt = 0; nt < 2; ++nt) {
      int boff = ((nt * 32 + kstep) * 64 + lr * 4 + lk) * 8;
      w_h[ks][nt] = *reinterpret_cast<const bf16x8*>(&Wh[boff]);
      w_l[ks][nt] = *reinterpret_cast<const bf16x8*>(&Wl[boff]);
    }
  }

  unsigned* fl = flags + g * 64;

  // initial xp prefetch (t=0) by the two reducer/packer waves (nt = kh)
  float xpv[4];
  if (kh < 2) {
    #pragma unroll
    for (int r = 0; r < 4; ++r)
      xpv[r] = xp[((size_t)0 * 64 + g * 16 + lk * 4 + r) * 1024 + c0 + kh * 16 + lr];
  }

  for (int t = 0; t < TT; ++t) {
    if (t > 0) {
      if (kh == 3) {             // single poller wave per WG
        int ok;
        do {
          unsigned v = __hip_atomic_load(&fl[lane], __ATOMIC_RELAXED,
                                         __HIP_MEMORY_SCOPE_AGENT);
          ok = ((int)v >= t);
        } while (!__all(ok));
      }
      __syncthreads();           // release: h(t) visible to everyone
    }
    const u64* hhq = hhi64 + (size_t)(t & 1) * 16384;
    const u64* hlq = hlo64 + (size_t)(t & 1) * 16384;
    f32x4 acc[2][2];
    #pragma unroll
    for (int nt = 0; nt < 2; ++nt)
      #pragma unroll
      for (int p = 0; p < 2; ++p) {
        acc[nt][p][0] = 0.f; acc[nt][p][1] = 0.f;
        acc[nt][p][2] = 0.f; acc[nt][p][3] = 0.f;
      }
    #pragma unroll
    for (int ks = 0; ks < 8; ++ks) {
      int kstep = kh * 8 + ks;
      int kb = kstep * 4 + lk;
      size_t ai = ((size_t)(g * 128 + kb) * 16 + lr) * 2;
      HU ua, ul;
      ua.q[0] = aload(hhq + ai); ua.q[1] = aload(hhq + ai + 1);
      ul.q[0] = aload(hlq + ai); ul.q[1] = aload(hlq + ai + 1);
      int p = ks & 1;
      #pragma unroll
      for (int nt = 0; nt < 2; ++nt) {
        acc[nt][p] = __builtin_amdgcn_mfma_f32_16x16x32_bf16(ua.v, w_h[ks][nt], acc[nt][p], 0, 0, 0);
        acc[nt][p] = __builtin_amdgcn_mfma_f32_16x16x32_bf16(ua.v, w_l[ks][nt], acc[nt][p], 0, 0, 0);
        acc[nt][p] = __builtin_amdgcn_mfma_f32_16x16x32_bf16(ul.v, w_h[ks][nt], acc[nt][p], 0, 0, 0);
      }
    }
    // all waves publish both nt partials
    #pragma unroll
    for (int nt = 0; nt < 2; ++nt) {
      f32x4 s;
      #pragma unroll
      for (int r = 0; r < 4; ++r) s[r] = acc[nt][0][r] + acc[nt][1][r];
      *reinterpret_cast<f32x4*>(&red[((kh * 2 + nt) * 64 + lane) * 4]) = s;
    }
    __syncthreads();                       // barrier1: red ready
    if (kh < 2) {                          // wave kh reduces nt=kh (4 vals/lane)
      int nt = kh;
      f32x4 s = *reinterpret_cast<const f32x4*>(&red[((0 * 2 + nt) * 64 + lane) * 4]);
      #pragma unroll
      for (int j = 1; j < 4; ++j) {
        f32x4 rv = *reinterpret_cast<const f32x4*>(&red[((j * 2 + nt) * 64 + lane) * 4]);
        #pragma unroll
        for (int r = 0; r < 4; ++r) s[r] += rv[r];
      }
      #pragma unroll
      for (int r = 0; r < 4; ++r) {
        float x = s[r] + xpv[r];
        float ex = __expf(2.0f * x);       // tanh = 1 - 2/(e^2x + 1)
        stage[(lk * 4 + r) * 32 + nt * 16 + lr] = 1.0f - 2.0f / (ex + 1.0f);
      }
    }
    __syncthreads();                       // barrier2: stage ready
    u64* nhq = hhi64 + (size_t)((t + 1) & 1) * 16384;
    u64* nlq = hlo64 + (size_t)((t + 1) & 1) * 16384;
    if (tid < 128) {                       // waves 0,1 pack + store + signal
      int idx = tid * 4;
      int cb = idx >> 7, rem = idx & 127, row2 = rem >> 3, e = rem & 7;
      float v0 = stage[row2 * 32 + cb * 8 + e + 0];
      float v1 = stage[row2 * 32 + cb * 8 + e + 1];
      float v2 = stage[row2 * 32 + cb * 8 + e + 2];
      float v3 = stage[row2 * 32 + cb * 8 + e + 3];
      short h0 = f2bf(v0), h1 = f2bf(v1), h2 = f2bf(v2), h3 = f2bf(v3);
      short l0 = f2bf(v0 - bf2f(h0)), l1 = f2bf(v1 - bf2f(h1));
      short l2 = f2bf(v2 - bf2f(h2)), l3 = f2bf(v3 - bf2f(h3));
      u64 hw = (u64)(uint16_t)h0 | ((u64)(uint16_t)h1 << 16) |
               ((u64)(uint16_t)h2 << 32) | ((u64)(uint16_t)h3 << 48);
      u64 lw = (u64)(uint16_t)l0 | ((u64)(uint16_t)l1 << 16) |
               ((u64)(uint16_t)l2 << 32) | ((u64)(uint16_t)l3 << 48);
      size_t off = ((size_t)(g * 128 + w * 4 + cb) * 16 + row2) * 2 + (e >> 2);
      astore(nhq + off, hw);
      astore(nlq + off, lw);
      if (t == TT - 1) {
        size_t o = (size_t)(g * 16 + row2) * 1024 + c0 + cb * 8 + e;
        float4v ov; ov[0] = v0; ov[1] = v1; ov[2] = v2; ov[3] = v3;
        *reinterpret_cast<float4v*>(&out[o]) = ov;
        *reinterpret_cast<float4v*>(&out[65536 + o]) = ov;
      }
      // drain own stores, fire this wave's subflag, then prefetch next xp
      asm volatile("s_waitcnt vmcnt(0)" ::: "memory");
      if (lane == 0)
        __hip_atomic_store(&fl[w * 2 + kh], (unsigned)(t + 1), __ATOMIC_RELAXED,
                           __HIP_MEMORY_SCOPE_AGENT);
      if (t + 1 < TT) {
        #pragma unroll
        for (int r = 0; r < 4; ++r)
          xpv[r] = xp[((size_t)(t + 1) * 64 + g * 16 + lk * 4 + r) * 1024 + c0 + kh * 16 + lr];
      }
    }
  }
}

extern "C" void kernel_launch(void* const* d_in, const int* in_sizes, int n_in,
                              void* d_out, int out_size, void* d_ws, size_t ws_size,
                              hipStream_t stream) {
  (void)in_sizes; (void)n_in; (void)out_size; (void)ws_size;
  const float* input      = (const float*)d_in[0];
  const float* init_state = (const float*)d_in[1];
  const float* W_ih       = (const float*)d_in[2];
  const float* W_hh       = (const float*)d_in[3];
  const float* bias       = (const float*)d_in[4];
  float* out = (float*)d_out;

  char* ws = (char*)d_ws;
  float* xp = (float*)ws;
  size_t off = (size_t)TT * BB * HH * 4;                 // 134.2 MB x_proj
  short* ih_hi = (short*)(ws + off); off += (size_t)DD * HH * 2;
  short* ih_lo = (short*)(ws + off); off += (size_t)DD * HH * 2;
  short* hh_hi = (short*)(ws + off); off += (size_t)HH * HH * 2;
  short* hh_lo = (short*)(ws + off); off += (size_t)HH * HH * 2;
  u64*   h_hi  = (u64*)(ws + off);   off += (size_t)2 * 16384 * 8;
  u64*   h_lo  = (u64*)(ws + off);   off += (size_t)2 * 16384 * 8;
  unsigned* flags = (unsigned*)(ws + off); off += (size_t)256 * 4;

  hipMemsetAsync(flags, 0, 256 * 4, stream);
  k_wsplit<<<512, 256, 0, stream>>>(W_ih, W_hh, ih_hi, ih_lo, hh_hi, hh_lo);
  k_gemm_xp<<<2048, 256, 0, stream>>>(input, ih_hi, ih_lo, bias, xp);
  k_init_h<<<256, 256, 0, stream>>>(init_state, (short*)h_hi, (short*)h_lo);
  k_rnn<<<128, 256, 0, stream>>>(xp, hh_hi, hh_lo, h_hi, h_lo, flags, out);
}

// Round 5
// 3209.605 us; speedup vs baseline: 1.0030x; 1.0030x over previous
//
#include <hip/hip_runtime.h>
#include <stdint.h>

#define TT 512
#define BB 64
#define DD 1024
#define HH 1024

typedef float    f32x4   __attribute__((ext_vector_type(4)));
typedef float    float4v __attribute__((ext_vector_type(4)));
typedef short    bf16x8  __attribute__((ext_vector_type(8)));
typedef short    short4v __attribute__((ext_vector_type(4)));
typedef uint32_t u32x4   __attribute__((ext_vector_type(4)));
typedef unsigned long long u64;

__device__ __forceinline__ short f2bf(float x) {
  uint32_t u = __builtin_bit_cast(uint32_t, x);
  u += 0x7fffu + ((u >> 16) & 1u);   // RNE to bf16
  return (short)(u >> 16);
}
__device__ __forceinline__ float bf2f(short s) {
  uint32_t u = ((uint32_t)(uint16_t)s) << 16;
  return __builtin_bit_cast(float, u);
}

union W4 { uint32_t w[4]; bf16x8 v; u32x4 q; };

// ---------------- W transpose + hi/lo split: W[k][n] f32 -> Wt_hi/lo[n][k] bf16 ----
__global__ __launch_bounds__(256) void k_wsplit(
    const float* __restrict__ Wih, const float* __restrict__ Whh,
    short* __restrict__ ih_hi, short* __restrict__ ih_lo,
    short* __restrict__ hh_hi, short* __restrict__ hh_lo)
{
  __shared__ float tile[64][65];
  int bid = blockIdx.x;
  int z = bid >> 8;              // 0: W_ih, 1: W_hh
  int tt = bid & 255;
  int tk = tt >> 4, tn = tt & 15;
  const float* __restrict__ src = z ? Whh : Wih;
  short* __restrict__ dhi = z ? hh_hi : ih_hi;
  short* __restrict__ dlo = z ? hh_lo : ih_lo;
  int k0 = tk * 64, n0 = tn * 64;
  int tid = threadIdx.x;
  #pragma unroll
  for (int i = 0; i < 4; ++i) {
    int idx = tid + i * 256;
    int r = idx >> 4, c4 = (idx & 15) * 4;
    float4v v = *reinterpret_cast<const float4v*>(&src[(size_t)(k0 + r) * HH + n0 + c4]);
    tile[r][c4 + 0] = v[0]; tile[r][c4 + 1] = v[1];
    tile[r][c4 + 2] = v[2]; tile[r][c4 + 3] = v[3];
  }
  __syncthreads();
  #pragma unroll
  for (int i = 0; i < 4; ++i) {
    int idx = tid + i * 256;
    int n = idx >> 4, kq = (idx & 15) * 4;
    short4v vh, vl;
    #pragma unroll
    for (int j = 0; j < 4; ++j) {
      float x = tile[kq + j][n];
      short h = f2bf(x);
      vh[j] = h;
      vl[j] = f2bf(x - bf2f(h));
    }
    *reinterpret_cast<short4v*>(&dhi[(size_t)(n0 + n) * 1024 + k0 + kq]) = vh;
    *reinterpret_cast<short4v*>(&dlo[(size_t)(n0 + n) * 1024 + k0 + kq]) = vl;
  }
}

// ---------------- x_proj GEMM: [32768 x 1024] = input @ W_ih + bias --------------
__global__ __launch_bounds__(256, 2) void k_gemm_xp(
    const float* __restrict__ A, const short* __restrict__ Bt_hi,
    const short* __restrict__ Bt_lo, const float* __restrict__ bias,
    float* __restrict__ xp)
{
  __shared__ __align__(16) short Ah[4096];
  __shared__ __align__(16) short Al[4096];
  __shared__ __align__(16) short Bh[4096];
  __shared__ __align__(16) short Bl[4096];
  int bid = blockIdx.x;
  int mb = bid & 255, nb = bid >> 8;
  size_t m0 = (size_t)mb * 128;
  int n0 = nb * 128;
  int tid = threadIdx.x;
  int lane = tid & 63, wid = tid >> 6;
  int wm = wid >> 1, wn = wid & 1;
  int lr = lane & 15, lk = lane >> 4;

  f32x4 acc[4][4];
  #pragma unroll
  for (int mt = 0; mt < 4; ++mt)
    #pragma unroll
    for (int nt = 0; nt < 4; ++nt) {
      acc[mt][nt][0] = 0.f; acc[mt][nt][1] = 0.f;
      acc[mt][nt][2] = 0.f; acc[mt][nt][3] = 0.f;
    }

  for (int kt = 0; kt < 32; ++kt) {
    int k0 = kt * 32;
    __syncthreads();
    #pragma unroll
    for (int i = 0; i < 4; ++i) {
      int idx = tid + i * 256;
      int r = idx >> 3, q = idx & 7;
      float4v v = *reinterpret_cast<const float4v*>(&A[(m0 + r) * 1024 + k0 + q * 4]);
      short4v vh, vl;
      #pragma unroll
      for (int j = 0; j < 4; ++j) {
        short h = f2bf(v[j]);
        vh[j] = h;
        vl[j] = f2bf(v[j] - bf2f(h));
      }
      int off = ((q >> 1) * 128 + r) * 8 + (q & 1) * 4;
      *reinterpret_cast<short4v*>(&Ah[off]) = vh;
      *reinterpret_cast<short4v*>(&Al[off]) = vl;
    }
    {
      int n = tid >> 1, half = tid & 1;
      size_t gb = (size_t)(n0 + n) * 1024 + k0 + half * 16;
      bf16x8 h0 = *reinterpret_cast<const bf16x8*>(&Bt_hi[gb]);
      bf16x8 h1 = *reinterpret_cast<const bf16x8*>(&Bt_hi[gb + 8]);
      bf16x8 l0 = *reinterpret_cast<const bf16x8*>(&Bt_lo[gb]);
      bf16x8 l1 = *reinterpret_cast<const bf16x8*>(&Bt_lo[gb + 8]);
      int kb = half * 2;
      *reinterpret_cast<bf16x8*>(&Bh[(kb * 128 + n) * 8]) = h0;
      *reinterpret_cast<bf16x8*>(&Bh[((kb + 1) * 128 + n) * 8]) = h1;
      *reinterpret_cast<bf16x8*>(&Bl[(kb * 128 + n) * 8]) = l0;
      *reinterpret_cast<bf16x8*>(&Bl[((kb + 1) * 128 + n) * 8]) = l1;
    }
    __syncthreads();

    bf16x8 a_h[4], a_l[4], b_h[4], b_l[4];
    #pragma unroll
    for (int mt = 0; mt < 4; ++mt) {
      int off = (lk * 128 + wm * 64 + mt * 16 + lr) * 8;
      a_h[mt] = *reinterpret_cast<const bf16x8*>(&Ah[off]);
      a_l[mt] = *reinterpret_cast<const bf16x8*>(&Al[off]);
    }
    #pragma unroll
    for (int nt = 0; nt < 4; ++nt) {
      int off = (lk * 128 + wn * 64 + nt * 16 + lr) * 8;
      b_h[nt] = *reinterpret_cast<const bf16x8*>(&Bh[off]);
      b_l[nt] = *reinterpret_cast<const bf16x8*>(&Bl[off]);
    }
    #pragma unroll
    for (int mt = 0; mt < 4; ++mt)
      #pragma unroll
      for (int nt = 0; nt < 4; ++nt) {
        acc[mt][nt] = __builtin_amdgcn_mfma_f32_16x16x32_bf16(a_h[mt], b_h[nt], acc[mt][nt], 0, 0, 0);
        acc[mt][nt] = __builtin_amdgcn_mfma_f32_16x16x32_bf16(a_h[mt], b_l[nt], acc[mt][nt], 0, 0, 0);
        acc[mt][nt] = __builtin_amdgcn_mfma_f32_16x16x32_bf16(a_l[mt], b_h[nt], acc[mt][nt], 0, 0, 0);
      }
  }
  #pragma unroll
  for (int nt = 0; nt < 4; ++nt) {
    int col = n0 + wn * 64 + nt * 16 + lr;
    float bv = bias[col];
    #pragma unroll
    for (int mt = 0; mt < 4; ++mt)
      #pragma unroll
      for (int r = 0; r < 4; ++r) {
        size_t row = m0 + wm * 64 + mt * 16 + lk * 4 + r;
        xp[row * 1024 + col] = acc[mt][nt][r] + bv;
      }
  }
}

// ---------------- pack init_state into interleaved h units --------------------
// unit (16B) = { hi bf16 x 4 cols | lo bf16 x 4 cols } for (g,kb,row,u)
__global__ __launch_bounds__(256) void k_init_h(
    const float* __restrict__ init, short* __restrict__ hs)
{
  int i = blockIdx.x * 256 + threadIdx.x;   // 0..65535
  float v = init[i];
  int b = i >> 10, n = i & 1023;
  int g = b >> 4, row = b & 15, kb = n >> 3, e = n & 7;
  int u = e >> 2, j = e & 3;
  size_t unit = ((size_t)(g * 128 + kb) * 16 + row) * 2 + u;
  short h = f2bf(v);
  hs[unit * 8 + j] = h;
  hs[unit * 8 + 4 + j] = f2bf(v - bf2f(h));
}

// ---------- asm MALL (sc0|sc1) 16B ops + 2-chunk pipelined loads -----------------
#define LD2(D0, D1, P)                                              \
  asm volatile("global_load_dwordx4 %0, %2, off sc0 sc1\n\t"        \
               "global_load_dwordx4 %1, %3, off sc0 sc1"            \
               : "=&v"(D0), "=&v"(D1)                               \
               : "v"(P), "v"((P) + 16) : "memory")

#define ISSUE4(BUF, CB)                                             \
  LD2(BUF[0], BUF[1], hk + ((CB) + 0) * 2048);                      \
  LD2(BUF[2], BUF[3], hk + ((CB) + 1) * 2048);                      \
  LD2(BUF[4], BUF[5], hk + ((CB) + 2) * 2048);                      \
  LD2(BUF[6], BUF[7], hk + ((CB) + 3) * 2048)

#define STEPQ(BUF, CB, Q) {                                         \
    W4 th_, tl_;                                                    \
    th_.w[0] = BUF[2*(Q)][0];   th_.w[1] = BUF[2*(Q)][1];           \
    th_.w[2] = BUF[2*(Q)+1][0]; th_.w[3] = BUF[2*(Q)+1][1];         \
    tl_.w[0] = BUF[2*(Q)][2];   tl_.w[1] = BUF[2*(Q)][3];           \
    tl_.w[2] = BUF[2*(Q)+1][2]; tl_.w[3] = BUF[2*(Q)+1][3];         \
    int boff_ = (wbase + ((CB) + (Q)) * 64) * 8;                    \
    bf16x8 bh_ = *reinterpret_cast<const bf16x8*>(&Wh[boff_]);      \
    bf16x8 bl_ = *reinterpret_cast<const bf16x8*>(&Wl[boff_]);      \
    f32x4& ac_ = ((Q) & 1) ? acc1 : acc0;                           \
    ac_ = __builtin_amdgcn_mfma_f32_16x16x32_bf16(th_.v, bh_, ac_, 0, 0, 0); \
    ac_ = __builtin_amdgcn_mfma_f32_16x16x32_bf16(th_.v, bl_, ac_, 0, 0, 0); \
    ac_ = __builtin_amdgcn_mfma_f32_16x16x32_bf16(tl_.v, bh_, ac_, 0, 0, 0); \
  }

#define COMPUTE4(BUF, CB)                                           \
  STEPQ(BUF, CB, 0); STEPQ(BUF, CB, 1);                             \
  STEPQ(BUF, CB, 2); STEPQ(BUF, CB, 3)

// ---------------- persistent recurrence: 512 steps, 4 groups x 32 WGs ------------
// R2 chassis: wave=(nt,kh); single per-(g,t) counter sync; wave-3 poller;
// interleaved 16B h units via asm dwordx4 sc0|sc1, 2-chunk vmcnt pipeline.
__global__ __launch_bounds__(256) void k_rnn(
    const float* __restrict__ xp,
    const short* __restrict__ whh_hi, const short* __restrict__ whh_lo,
    char* __restrict__ hbuf,
    unsigned* __restrict__ cnt, float* __restrict__ out)
{
  __shared__ __align__(16) short Wh[32768];   // fragment-major [nt][kstep][lr*4+lk][8]
  __shared__ __align__(16) short Wl[32768];
  __shared__ __align__(16) float red[2 * 64 * 4];   // [nt][lane][4] from kh==1 waves
  __shared__ __align__(16) float stage[512];        // [row16][col32]

  int bid = blockIdx.x;
  int g = bid & 3;               // batch-row group: rows g*16..+16
  int w = bid >> 2;              // 0..31: column slice
  int c0 = w * 32;
  int tid = threadIdx.x;
  int lane = tid & 63, wid = tid >> 6;
  int nt = wid & 1, kh = wid >> 1;   // wave = (N-tile, K-half of 16 ksteps)
  int lr = lane & 15, lk = lane >> 4;

  // one-time: W slice fragment-major into LDS
  {
    int combo = tid >> 1, ksh = tid & 1;
    int colw = combo >> 2, lkf = combo & 3;
    int ntf = colw >> 4, lrf = colw & 15;
    #pragma unroll
    for (int j = 0; j < 16; ++j) {
      int kstep = ksh * 16 + j;
      int dst = ((ntf * 32 + kstep) * 64 + lrf * 4 + lkf) * 8;
      size_t src = (size_t)(c0 + colw) * 1024 + kstep * 32 + lkf * 8;
      *reinterpret_cast<bf16x8*>(&Wh[dst]) = *reinterpret_cast<const bf16x8*>(&whh_hi[src]);
      *reinterpret_cast<bf16x8*>(&Wl[dst]) = *reinterpret_cast<const bf16x8*>(&whh_lo[src]);
    }
  }
  __syncthreads();

  unsigned* fl = cnt + g * 512;
  const int wbase = (nt * 32 + kh * 16) * 64 + lr * 4 + lk;

  for (int t = 0; t < TT; ++t) {
    if (t > 0) {
      if (tid == 255) {          // wave-3 poller: overlaps producers' drain
        while (__hip_atomic_load(&fl[t - 1], __ATOMIC_RELAXED,
                                 __HIP_MEMORY_SCOPE_AGENT) < 64u)
          __builtin_amdgcn_s_sleep(1);
      }
      __syncthreads();           // release: h(t) visible to everyone
    }
    // xp[t] for this wave's nt-columns (packer waves kh==0 only); issued before
    // the asm chunk loads, fully drained by our explicit vmcnt(0) below.
    float xpv[4];
    if (kh == 0) {
      #pragma unroll
      for (int r = 0; r < 4; ++r)
        xpv[r] = xp[((size_t)t * 64 + g * 16 + lk * 4 + r) * 1024 + c0 + nt * 16 + lr];
    }

    const char* hb = hbuf + (size_t)(t & 1) * 262144 + g * 65536 + lk * 512 + lr * 32;
    const char* hk = hb + kh * 32768;
    u32x4 bufA[8], bufB[8];
    f32x4 acc0, acc1;
    acc0[0]=0.f; acc0[1]=0.f; acc0[2]=0.f; acc0[3]=0.f;
    acc1 = acc0;

    ISSUE4(bufA, 0);
    ISSUE4(bufB, 4);
    asm volatile("s_waitcnt vmcnt(8)" ::: "memory");
    __builtin_amdgcn_sched_barrier(0);
    COMPUTE4(bufA, 0);
    ISSUE4(bufA, 8);
    asm volatile("s_waitcnt vmcnt(8)" ::: "memory");
    __builtin_amdgcn_sched_barrier(0);
    COMPUTE4(bufB, 4);
    ISSUE4(bufB, 12);
    asm volatile("s_waitcnt vmcnt(8)" ::: "memory");
    __builtin_amdgcn_sched_barrier(0);
    COMPUTE4(bufA, 8);
    asm volatile("s_waitcnt vmcnt(0)" ::: "memory");
    __builtin_amdgcn_sched_barrier(0);
    COMPUTE4(bufB, 12);

    if (kh == 1) {               // publish partials
      f32x4 s;
      #pragma unroll
      for (int r = 0; r < 4; ++r) s[r] = acc0[r] + acc1[r];
      *reinterpret_cast<f32x4*>(&red[(nt * 64 + lane) * 4]) = s;
    }
    __syncthreads();             // barrier1: red ready
    if (kh == 0) {               // reduce + tanh (wave nt handles its own cols)
      f32x4 rv = *reinterpret_cast<const f32x4*>(&red[(nt * 64 + lane) * 4]);
      #pragma unroll
      for (int r = 0; r < 4; ++r) {
        float x = acc0[r] + acc1[r] + rv[r] + xpv[r];
        float ex = __expf(2.0f * x);       // tanh = 1 - 2/(e^2x + 1)
        stage[(lk * 4 + r) * 32 + nt * 16 + lr] = 1.0f - 2.0f / (ex + 1.0f);
      }
    }
    __syncthreads();             // barrier2: stage ready
    if (tid < 128) {             // waves 0,1: pack 1 unit each, store, signal
      int kb_local = tid >> 5, rem = tid & 31, row = rem >> 1, u = rem & 1;
      int lcol = kb_local * 8 + u * 4;
      float4v sv = *reinterpret_cast<const float4v*>(&stage[row * 32 + lcol]);
      short h0 = f2bf(sv[0]), h1 = f2bf(sv[1]), h2 = f2bf(sv[2]), h3 = f2bf(sv[3]);
      short l0 = f2bf(sv[0] - bf2f(h0)), l1 = f2bf(sv[1] - bf2f(h1));
      short l2 = f2bf(sv[2] - bf2f(h2)), l3 = f2bf(sv[3] - bf2f(h3));
      W4 val;
      val.w[0] = (uint32_t)(uint16_t)h0 | ((uint32_t)(uint16_t)h1 << 16);
      val.w[1] = (uint32_t)(uint16_t)h2 | ((uint32_t)(uint16_t)h3 << 16);
      val.w[2] = (uint32_t)(uint16_t)l0 | ((uint32_t)(uint16_t)l1 << 16);
      val.w[3] = (uint32_t)(uint16_t)l2 | ((uint32_t)(uint16_t)l3 << 16);
      char* np = hbuf + (size_t)((t + 1) & 1) * 262144 +
                 (((size_t)(g * 128 + w * 4 + kb_local) * 16 + row) * 2 + u) * 16;
      asm volatile("global_store_dwordx4 %0, %1, off sc0 sc1"
                   :: "v"(np), "v"(val.q) : "memory");
      if (t == TT - 1) {
        size_t o = (size_t)(g * 16 + row) * 1024 + c0 + lcol;
        *reinterpret_cast<float4v*>(&out[o]) = sv;
        *reinterpret_cast<float4v*>(&out[65536 + o]) = sv;
      }
      // per-wave drain, then one counter add per wave (64 per group total)
      asm volatile("s_waitcnt vmcnt(0)" ::: "memory");
      if (lane == 0)
        __hip_atomic_fetch_add(&fl[t], 1u, __ATOMIC_RELAXED,
                               __HIP_MEMORY_SCOPE_AGENT);
    }
  }
}

extern "C" void kernel_launch(void* const* d_in, const int* in_sizes, int n_in,
                              void* d_out, int out_size, void* d_ws, size_t ws_size,
                              hipStream_t stream) {
  (void)in_sizes; (void)n_in; (void)out_size; (void)ws_size;
  const float* input      = (const float*)d_in[0];
  const float* init_state = (const float*)d_in[1];
  const float* W_ih       = (const float*)d_in[2];
  const float* W_hh       = (const float*)d_in[3];
  const float* bias       = (const float*)d_in[4];
  float* out = (float*)d_out;

  char* ws = (char*)d_ws;
  float* xp = (float*)ws;
  size_t off = (size_t)TT * BB * HH * 4;                 // 134.2 MB x_proj
  short* ih_hi = (short*)(ws + off); off += (size_t)DD * HH * 2;
  short* ih_lo = (short*)(ws + off); off += (size_t)DD * HH * 2;
  short* hh_hi = (short*)(ws + off); off += (size_t)HH * HH * 2;
  short* hh_lo = (short*)(ws + off); off += (size_t)HH * HH * 2;
  char*  hbuf  = ws + off;           off += (size_t)2 * 262144;   // 512 KB, 2 parities
  unsigned* cnt = (unsigned*)(ws + off); off += (size_t)2048 * 4;

  hipMemsetAsync(cnt, 0, 2048 * 4, stream);
  k_wsplit<<<512, 256, 0, stream>>>(W_ih, W_hh, ih_hi, ih_lo, hh_hi, hh_lo);
  k_gemm_xp<<<2048, 256, 0, stream>>>(input, ih_hi, ih_lo, bias, xp);
  k_init_h<<<256, 256, 0, stream>>>(init_state, (short*)hbuf);
  k_rnn<<<128, 256, 0, stream>>>(xp, hh_hi, hh_lo, hbuf, cnt, out);
}

// Round 6
// 3116.722 us; speedup vs baseline: 1.0329x; 1.0298x over previous
//
#include <hip/hip_runtime.h>
#include <stdint.h>

#define TT 512
#define BB 64
#define DD 1024
#define HH 1024

typedef float  f32x4   __attribute__((ext_vector_type(4)));
typedef float  float4v __attribute__((ext_vector_type(4)));
typedef short  bf16x8  __attribute__((ext_vector_type(8)));
typedef short  short4v __attribute__((ext_vector_type(4)));
typedef unsigned long long u64;

__device__ __forceinline__ short f2bf(float x) {
  uint32_t u = __builtin_bit_cast(uint32_t, x);
  u += 0x7fffu + ((u >> 16) & 1u);   // RNE to bf16
  return (short)(u >> 16);
}
__device__ __forceinline__ float bf2f(short s) {
  uint32_t u = ((uint32_t)(uint16_t)s) << 16;
  return __builtin_bit_cast(float, u);
}

// MALL-coherent (agent-scope, L1/L2-bypassing) accesses — no cache flushes.
__device__ __forceinline__ u64 aload(const u64* p) {
  return __hip_atomic_load(p, __ATOMIC_RELAXED, __HIP_MEMORY_SCOPE_AGENT);
}
__device__ __forceinline__ void astore(u64* p, u64 v) {
  __hip_atomic_store(p, v, __ATOMIC_RELAXED, __HIP_MEMORY_SCOPE_AGENT);
}

union HU { u64 q[2]; bf16x8 v; };

// ---------------- W transpose + hi/lo split: W[k][n] f32 -> Wt_hi/lo[n][k] bf16 ----
__global__ __launch_bounds__(256) void k_wsplit(
    const float* __restrict__ Wih, const float* __restrict__ Whh,
    short* __restrict__ ih_hi, short* __restrict__ ih_lo,
    short* __restrict__ hh_hi, short* __restrict__ hh_lo)
{
  __shared__ float tile[64][65];
  int bid = blockIdx.x;
  int z = bid >> 8;              // 0: W_ih, 1: W_hh
  int tt = bid & 255;
  int tk = tt >> 4, tn = tt & 15;
  const float* __restrict__ src = z ? Whh : Wih;
  short* __restrict__ dhi = z ? hh_hi : ih_hi;
  short* __restrict__ dlo = z ? hh_lo : ih_lo;
  int k0 = tk * 64, n0 = tn * 64;
  int tid = threadIdx.x;
  #pragma unroll
  for (int i = 0; i < 4; ++i) {
    int idx = tid + i * 256;
    int r = idx >> 4, c4 = (idx & 15) * 4;
    float4v v = *reinterpret_cast<const float4v*>(&src[(size_t)(k0 + r) * HH + n0 + c4]);
    tile[r][c4 + 0] = v[0]; tile[r][c4 + 1] = v[1];
    tile[r][c4 + 2] = v[2]; tile[r][c4 + 3] = v[3];
  }
  __syncthreads();
  #pragma unroll
  for (int i = 0; i < 4; ++i) {
    int idx = tid + i * 256;
    int n = idx >> 4, kq = (idx & 15) * 4;
    short4v vh, vl;
    #pragma unroll
    for (int j = 0; j < 4; ++j) {
      float x = tile[kq + j][n];
      short h = f2bf(x);
      vh[j] = h;
      vl[j] = f2bf(x - bf2f(h));
    }
    *reinterpret_cast<short4v*>(&dhi[(size_t)(n0 + n) * 1024 + k0 + kq]) = vh;
    *reinterpret_cast<short4v*>(&dlo[(size_t)(n0 + n) * 1024 + k0 + kq]) = vl;
  }
}

// ---------------- x_proj GEMM: [32768 x 1024] = input @ W_ih + bias --------------
__global__ __launch_bounds__(256, 2) void k_gemm_xp(
    const float* __restrict__ A, const short* __restrict__ Bt_hi,
    const short* __restrict__ Bt_lo, const float* __restrict__ bias,
    float* __restrict__ xp)
{
  __shared__ __align__(16) short Ah[4096];
  __shared__ __align__(16) short Al[4096];
  __shared__ __align__(16) short Bh[4096];
  __shared__ __align__(16) short Bl[4096];
  int bid = blockIdx.x;
  int mb = bid & 255, nb = bid >> 8;
  size_t m0 = (size_t)mb * 128;
  int n0 = nb * 128;
  int tid = threadIdx.x;
  int lane = tid & 63, wid = tid >> 6;
  int wm = wid >> 1, wn = wid & 1;
  int lr = lane & 15, lk = lane >> 4;

  f32x4 acc[4][4];
  #pragma unroll
  for (int mt = 0; mt < 4; ++mt)
    #pragma unroll
    for (int nt = 0; nt < 4; ++nt) {
      acc[mt][nt][0] = 0.f; acc[mt][nt][1] = 0.f;
      acc[mt][nt][2] = 0.f; acc[mt][nt][3] = 0.f;
    }

  for (int kt = 0; kt < 32; ++kt) {
    int k0 = kt * 32;
    __syncthreads();
    #pragma unroll
    for (int i = 0; i < 4; ++i) {
      int idx = tid + i * 256;
      int r = idx >> 3, q = idx & 7;
      float4v v = *reinterpret_cast<const float4v*>(&A[(m0 + r) * 1024 + k0 + q * 4]);
      short4v vh, vl;
      #pragma unroll
      for (int j = 0; j < 4; ++j) {
        short h = f2bf(v[j]);
        vh[j] = h;
        vl[j] = f2bf(v[j] - bf2f(h));
      }
      int off = ((q >> 1) * 128 + r) * 8 + (q & 1) * 4;
      *reinterpret_cast<short4v*>(&Ah[off]) = vh;
      *reinterpret_cast<short4v*>(&Al[off]) = vl;
    }
    {
      int n = tid >> 1, half = tid & 1;
      size_t gb = (size_t)(n0 + n) * 1024 + k0 + half * 16;
      bf16x8 h0 = *reinterpret_cast<const bf16x8*>(&Bt_hi[gb]);
      bf16x8 h1 = *reinterpret_cast<const bf16x8*>(&Bt_hi[gb + 8]);
      bf16x8 l0 = *reinterpret_cast<const bf16x8*>(&Bt_lo[gb]);
      bf16x8 l1 = *reinterpret_cast<const bf16x8*>(&Bt_lo[gb + 8]);
      int kb = half * 2;
      *reinterpret_cast<bf16x8*>(&Bh[(kb * 128 + n) * 8]) = h0;
      *reinterpret_cast<bf16x8*>(&Bh[((kb + 1) * 128 + n) * 8]) = h1;
      *reinterpret_cast<bf16x8*>(&Bl[(kb * 128 + n) * 8]) = l0;
      *reinterpret_cast<bf16x8*>(&Bl[((kb + 1) * 128 + n) * 8]) = l1;
    }
    __syncthreads();

    bf16x8 a_h[4], a_l[4], b_h[4], b_l[4];
    #pragma unroll
    for (int mt = 0; mt < 4; ++mt) {
      int off = (lk * 128 + wm * 64 + mt * 16 + lr) * 8;
      a_h[mt] = *reinterpret_cast<const bf16x8*>(&Ah[off]);
      a_l[mt] = *reinterpret_cast<const bf16x8*>(&Al[off]);
    }
    #pragma unroll
    for (int nt = 0; nt < 4; ++nt) {
      int off = (lk * 128 + wn * 64 + nt * 16 + lr) * 8;
      b_h[nt] = *reinterpret_cast<const bf16x8*>(&Bh[off]);
      b_l[nt] = *reinterpret_cast<const bf16x8*>(&Bl[off]);
    }
    #pragma unroll
    for (int mt = 0; mt < 4; ++mt)
      #pragma unroll
      for (int nt = 0; nt < 4; ++nt) {
        acc[mt][nt] = __builtin_amdgcn_mfma_f32_16x16x32_bf16(a_h[mt], b_h[nt], acc[mt][nt], 0, 0, 0);
        acc[mt][nt] = __builtin_amdgcn_mfma_f32_16x16x32_bf16(a_h[mt], b_l[nt], acc[mt][nt], 0, 0, 0);
        acc[mt][nt] = __builtin_amdgcn_mfma_f32_16x16x32_bf16(a_l[mt], b_h[nt], acc[mt][nt], 0, 0, 0);
      }
  }
  #pragma unroll
  for (int nt = 0; nt < 4; ++nt) {
    int col = n0 + wn * 64 + nt * 16 + lr;
    float bv = bias[col];
    #pragma unroll
    for (int mt = 0; mt < 4; ++mt)
      #pragma unroll
      for (int r = 0; r < 4; ++r) {
        size_t row = m0 + wm * 64 + mt * 16 + lk * 4 + r;
        xp[row * 1024 + col] = acc[mt][nt][r] + bv;
      }
  }
}

// ---------------- pack init_state into h plane layout [g][kb128][row16][8] --------
__global__ __launch_bounds__(256) void k_init_h(
    const float* __restrict__ init, short* __restrict__ hhi, short* __restrict__ hlo)
{
  int i = blockIdx.x * 256 + threadIdx.x;   // 0..65535
  float v = init[i];
  int b = i >> 10, n = i & 1023;
  int g = b >> 4, row = b & 15, kb = n >> 3, e = n & 7;
  size_t off = ((size_t)(g * 128 + kb) * 16 + row) * 8 + e;
  short h = f2bf(v);
  hhi[off] = h;
  hlo[off] = f2bf(v - bf2f(h));
}

// ---------------- persistent recurrence: 512 steps, 4 groups x 32 WGs ------------
// R2 chassis (wave=(nt,kh), single counter + 32 RMW, scalar poll + s_sleep,
// u64 MALL h traffic, nt-duplicated loads). R6 changes: wave-0-only tail
// (reduce+tanh+pack+store+drain+signal), wave-3 poller overlapping the tail,
// 2 barriers/step instead of 4, fragment-major W LDS, padded stage.
__global__ __launch_bounds__(256) void k_rnn(
    const float* __restrict__ xp,
    const short* __restrict__ whh_hi, const short* __restrict__ whh_lo,
    u64* __restrict__ hhi64, u64* __restrict__ hlo64,
    unsigned* __restrict__ cnt, float* __restrict__ out)
{
  __shared__ __align__(16) short Wh[32768];   // fragment-major [nt][kstep][lr*4+lk][8]
  __shared__ __align__(16) short Wl[32768];
  __shared__ __align__(16) float red[3 * 64 * 4];   // partials from waves 1,2,3
  __shared__ __align__(16) float stage[16 * 36];    // [row16][col32 pad+4]

  int bid = blockIdx.x;
  int g = bid & 3;               // batch-row group: rows g*16..+16
  int w = bid >> 2;              // 0..31: column slice
  int c0 = w * 32;
  int tid = threadIdx.x;
  int lane = tid & 63, wid = tid >> 6;
  int nt = wid & 1, kh = wid >> 1;   // wave = (N-tile, K-half of 16 ksteps)
  int lr = lane & 15, lk = lane >> 4;

  // one-time: W slice fragment-major into LDS (proven R3/R4/R5)
  {
    int combo = tid >> 1, ksh = tid & 1;
    int colw = combo >> 2, lkf = combo & 3;
    int ntf = colw >> 4, lrf = colw & 15;
    #pragma unroll
    for (int j = 0; j < 16; ++j) {
      int kstep = ksh * 16 + j;
      int dst = ((ntf * 32 + kstep) * 64 + lrf * 4 + lkf) * 8;
      size_t src = (size_t)(c0 + colw) * 1024 + kstep * 32 + lkf * 8;
      *reinterpret_cast<bf16x8*>(&Wh[dst]) = *reinterpret_cast<const bf16x8*>(&whh_hi[src]);
      *reinterpret_cast<bf16x8*>(&Wl[dst]) = *reinterpret_cast<const bf16x8*>(&whh_lo[src]);
    }
  }
  __syncthreads();

  unsigned* fl = cnt + g * 512;

  for (int t = 0; t < TT; ++t) {
    // wave 0 prefetches xp[t] for both nt BEFORE the release barrier (hidden)
    float xpv[2][4];
    if (wid == 0) {
      #pragma unroll
      for (int ntt = 0; ntt < 2; ++ntt)
        #pragma unroll
        for (int r = 0; r < 4; ++r)
          xpv[ntt][r] = xp[((size_t)t * 64 + g * 16 + lk * 4 + r) * 1024 + c0 + ntt * 16 + lr];
    }
    if (t > 0) {
      if (tid == 192) {          // wave-3 poller: overlaps wave 0's tail of t-1
        while (__hip_atomic_load(&fl[t - 1], __ATOMIC_RELAXED,
                                 __HIP_MEMORY_SCOPE_AGENT) < 32u)
          __builtin_amdgcn_s_sleep(1);
      }
      __syncthreads();           // release: h(t) visible to everyone
    }
    const u64* hhq = hhi64 + (size_t)(t & 1) * 16384;
    const u64* hlq = hlo64 + (size_t)(t & 1) * 16384;
    f32x4 acc0, acc1;
    acc0[0]=0.f; acc0[1]=0.f; acc0[2]=0.f; acc0[3]=0.f;
    acc1 = acc0;
    #pragma unroll 8
    for (int ks = 0; ks < 16; ++ks) {
      int kstep = kh * 16 + ks;
      int kb = kstep * 4 + lk;
      size_t ai = ((size_t)(g * 128 + kb) * 16 + lr) * 2;
      HU ua, ul;
      ua.q[0] = aload(hhq + ai); ua.q[1] = aload(hhq + ai + 1);
      ul.q[0] = aload(hlq + ai); ul.q[1] = aload(hlq + ai + 1);
      int boff = ((nt * 32 + kstep) * 64 + lr * 4 + lk) * 8;
      bf16x8 bh = *reinterpret_cast<const bf16x8*>(&Wh[boff]);
      bf16x8 bl = *reinterpret_cast<const bf16x8*>(&Wl[boff]);
      if ((ks & 1) == 0) {
        acc0 = __builtin_amdgcn_mfma_f32_16x16x32_bf16(ua.v, bh, acc0, 0, 0, 0);
        acc0 = __builtin_amdgcn_mfma_f32_16x16x32_bf16(ua.v, bl, acc0, 0, 0, 0);
        acc0 = __builtin_amdgcn_mfma_f32_16x16x32_bf16(ul.v, bh, acc0, 0, 0, 0);
      } else {
        acc1 = __builtin_amdgcn_mfma_f32_16x16x32_bf16(ua.v, bh, acc1, 0, 0, 0);
        acc1 = __builtin_amdgcn_mfma_f32_16x16x32_bf16(ua.v, bl, acc1, 0, 0, 0);
        acc1 = __builtin_amdgcn_mfma_f32_16x16x32_bf16(ul.v, bh, acc1, 0, 0, 0);
      }
    }
    // waves 1,2,3 publish partials; wave 0 keeps its own in regs
    if (wid != 0) {
      f32x4 s;
      #pragma unroll
      for (int r = 0; r < 4; ++r) s[r] = acc0[r] + acc1[r];
      *reinterpret_cast<f32x4*>(&red[((wid - 1) * 64 + lane) * 4]) = s;
    }
    __syncthreads();             // barrier1: red ready
    if (wid == 0) {              // wave-0-only tail
      // nt=0: own acc + wave2 (nt0,kh1);  nt=1: wave1 (nt1,kh0) + wave3 (nt1,kh1)
      f32x4 r1 = *reinterpret_cast<const f32x4*>(&red[(1 * 64 + lane) * 4]);
      f32x4 r0 = *reinterpret_cast<const f32x4*>(&red[(0 * 64 + lane) * 4]);
      f32x4 r2 = *reinterpret_cast<const f32x4*>(&red[(2 * 64 + lane) * 4]);
      #pragma unroll
      for (int r = 0; r < 4; ++r) {
        float x0 = acc0[r] + acc1[r] + r1[r] + xpv[0][r];
        float e0 = __expf(2.0f * x0);
        stage[(lk * 4 + r) * 36 + lr] = 1.0f - 2.0f / (e0 + 1.0f);
        float x1 = r0[r] + r2[r] + xpv[1][r];
        float e1 = __expf(2.0f * x1);
        stage[(lk * 4 + r) * 36 + 16 + lr] = 1.0f - 2.0f / (e1 + 1.0f);
      }
      // pack 2 units/lane (wave-local LDS ordering; no block barrier needed)
      u64* nhq = hhi64 + (size_t)((t + 1) & 1) * 16384;
      u64* nlq = hlo64 + (size_t)((t + 1) & 1) * 16384;
      #pragma unroll
      for (int s = 0; s < 2; ++s) {
        int unit = lane * 2 + s;
        int kbl = unit >> 5, rem = unit & 31, row = rem >> 1, uu = rem & 1;
        int lcol = kbl * 8 + uu * 4;
        float4v sv = *reinterpret_cast<const float4v*>(&stage[row * 36 + lcol]);
        short h0 = f2bf(sv[0]), h1 = f2bf(sv[1]), h2 = f2bf(sv[2]), h3 = f2bf(sv[3]);
        short l0 = f2bf(sv[0] - bf2f(h0)), l1 = f2bf(sv[1] - bf2f(h1));
        short l2 = f2bf(sv[2] - bf2f(h2)), l3 = f2bf(sv[3] - bf2f(h3));
        u64 hw = (u64)(uint16_t)h0 | ((u64)(uint16_t)h1 << 16) |
                 ((u64)(uint16_t)h2 << 32) | ((u64)(uint16_t)h3 << 48);
        u64 lw = (u64)(uint16_t)l0 | ((u64)(uint16_t)l1 << 16) |
                 ((u64)(uint16_t)l2 << 32) | ((u64)(uint16_t)l3 << 48);
        size_t off = ((size_t)(g * 128 + w * 4 + kbl) * 16 + row) * 2 + uu;
        astore(nhq + off, hw);
        astore(nlq + off, lw);
        if (t == TT - 1) {
          size_t o = (size_t)(g * 16 + row) * 1024 + c0 + lcol;
          *reinterpret_cast<float4v*>(&out[o]) = sv;
          *reinterpret_cast<float4v*>(&out[65536 + o]) = sv;
        }
      }
      // drain own stores, then single counter RMW (32 per group)
      asm volatile("s_waitcnt vmcnt(0)" ::: "memory");
      if (lane == 0)
        __hip_atomic_fetch_add(&fl[t], 1u, __ATOMIC_RELAXED,
                               __HIP_MEMORY_SCOPE_AGENT);
    }
  }
}

extern "C" void kernel_launch(void* const* d_in, const int* in_sizes, int n_in,
                              void* d_out, int out_size, void* d_ws, size_t ws_size,
                              hipStream_t stream) {
  (void)in_sizes; (void)n_in; (void)out_size; (void)ws_size;
  const float* input      = (const float*)d_in[0];
  const float* init_state = (const float*)d_in[1];
  const float* W_ih       = (const float*)d_in[2];
  const float* W_hh       = (const float*)d_in[3];
  const float* bias       = (const float*)d_in[4];
  float* out = (float*)d_out;

  char* ws = (char*)d_ws;
  float* xp = (float*)ws;
  size_t off = (size_t)TT * BB * HH * 4;                 // 134.2 MB x_proj
  short* ih_hi = (short*)(ws + off); off += (size_t)DD * HH * 2;
  short* ih_lo = (short*)(ws + off); off += (size_t)DD * HH * 2;
  short* hh_hi = (short*)(ws + off); off += (size_t)HH * HH * 2;
  short* hh_lo = (short*)(ws + off); off += (size_t)HH * HH * 2;
  u64*   h_hi  = (u64*)(ws + off);   off += (size_t)2 * 16384 * 8;
  u64*   h_lo  = (u64*)(ws + off);   off += (size_t)2 * 16384 * 8;
  unsigned* cnt = (unsigned*)(ws + off); off += (size_t)2048 * 4;

  hipMemsetAsync(cnt, 0, 2048 * 4, stream);
  k_wsplit<<<512, 256, 0, stream>>>(W_ih, W_hh, ih_hi, ih_lo, hh_hi, hh_lo);
  k_gemm_xp<<<2048, 256, 0, stream>>>(input, ih_hi, ih_lo, bias, xp);
  k_init_h<<<256, 256, 0, stream>>>(init_state, (short*)h_hi, (short*)h_lo);
  k_rnn<<<128, 256, 0, stream>>>(xp, hh_hi, hh_lo, h_hi, h_lo, cnt, out);
}

// Round 7
// 2305.801 us; speedup vs baseline: 1.3962x; 1.3517x over previous
//
#include <hip/hip_runtime.h>
#include <stdint.h>

#define TT 512
#define BB 64
#define DD 1024
#define HH 1024

typedef float  f32x4   __attribute__((ext_vector_type(4)));
typedef float  float4v __attribute__((ext_vector_type(4)));
typedef short  bf16x8  __attribute__((ext_vector_type(8)));
typedef short  short4v __attribute__((ext_vector_type(4)));
typedef unsigned long long u64;

__device__ __forceinline__ short f2bf(float x) {
  uint32_t u = __builtin_bit_cast(uint32_t, x);
  u += 0x7fffu + ((u >> 16) & 1u);   // RNE to bf16
  return (short)(u >> 16);
}
__device__ __forceinline__ float bf2f(short s) {
  uint32_t u = ((uint32_t)(uint16_t)s) << 16;
  return __builtin_bit_cast(float, u);
}

// MALL-coherent (agent-scope, L1/L2-bypassing) accesses — no cache flushes.
__device__ __forceinline__ u64 aload(const u64* p) {
  return __hip_atomic_load(p, __ATOMIC_RELAXED, __HIP_MEMORY_SCOPE_AGENT);
}
__device__ __forceinline__ void astore(u64* p, u64 v) {
  __hip_atomic_store(p, v, __ATOMIC_RELAXED, __HIP_MEMORY_SCOPE_AGENT);
}

union HU { u64 q[2]; bf16x8 v; };

// ---------------- W transpose + hi/lo split: W[k][n] f32 -> Wt_hi/lo[n][k] bf16 ----
__global__ __launch_bounds__(256) void k_wsplit(
    const float* __restrict__ Wih, const float* __restrict__ Whh,
    short* __restrict__ ih_hi, short* __restrict__ ih_lo,
    short* __restrict__ hh_hi, short* __restrict__ hh_lo)
{
  __shared__ float tile[64][65];
  int bid = blockIdx.x;
  int z = bid >> 8;              // 0: W_ih, 1: W_hh
  int tt = bid & 255;
  int tk = tt >> 4, tn = tt & 15;
  const float* __restrict__ src = z ? Whh : Wih;
  short* __restrict__ dhi = z ? hh_hi : ih_hi;
  short* __restrict__ dlo = z ? hh_lo : ih_lo;
  int k0 = tk * 64, n0 = tn * 64;
  int tid = threadIdx.x;
  #pragma unroll
  for (int i = 0; i < 4; ++i) {
    int idx = tid + i * 256;
    int r = idx >> 4, c4 = (idx & 15) * 4;
    float4v v = *reinterpret_cast<const float4v*>(&src[(size_t)(k0 + r) * HH + n0 + c4]);
    tile[r][c4 + 0] = v[0]; tile[r][c4 + 1] = v[1];
    tile[r][c4 + 2] = v[2]; tile[r][c4 + 3] = v[3];
  }
  __syncthreads();
  #pragma unroll
  for (int i = 0; i < 4; ++i) {
    int idx = tid + i * 256;
    int n = idx >> 4, kq = (idx & 15) * 4;
    short4v vh, vl;
    #pragma unroll
    for (int j = 0; j < 4; ++j) {
      float x = tile[kq + j][n];
      short h = f2bf(x);
      vh[j] = h;
      vl[j] = f2bf(x - bf2f(h));
    }
    *reinterpret_cast<short4v*>(&dhi[(size_t)(n0 + n) * 1024 + k0 + kq]) = vh;
    *reinterpret_cast<short4v*>(&dlo[(size_t)(n0 + n) * 1024 + k0 + kq]) = vl;
  }
}

// ---------------- x_proj GEMM: [32768 x 1024] = input @ W_ih + bias --------------
__global__ __launch_bounds__(256, 2) void k_gemm_xp(
    const float* __restrict__ A, const short* __restrict__ Bt_hi,
    const short* __restrict__ Bt_lo, const float* __restrict__ bias,
    float* __restrict__ xp)
{
  __shared__ __align__(16) short Ah[4096];
  __shared__ __align__(16) short Al[4096];
  __shared__ __align__(16) short Bh[4096];
  __shared__ __align__(16) short Bl[4096];
  int bid = blockIdx.x;
  int mb = bid & 255, nb = bid >> 8;
  size_t m0 = (size_t)mb * 128;
  int n0 = nb * 128;
  int tid = threadIdx.x;
  int lane = tid & 63, wid = tid >> 6;
  int wm = wid >> 1, wn = wid & 1;
  int lr = lane & 15, lk = lane >> 4;

  f32x4 acc[4][4];
  #pragma unroll
  for (int mt = 0; mt < 4; ++mt)
    #pragma unroll
    for (int nt = 0; nt < 4; ++nt) {
      acc[mt][nt][0] = 0.f; acc[mt][nt][1] = 0.f;
      acc[mt][nt][2] = 0.f; acc[mt][nt][3] = 0.f;
    }

  for (int kt = 0; kt < 32; ++kt) {
    int k0 = kt * 32;
    __syncthreads();
    #pragma unroll
    for (int i = 0; i < 4; ++i) {
      int idx = tid + i * 256;
      int r = idx >> 3, q = idx & 7;
      float4v v = *reinterpret_cast<const float4v*>(&A[(m0 + r) * 1024 + k0 + q * 4]);
      short4v vh, vl;
      #pragma unroll
      for (int j = 0; j < 4; ++j) {
        short h = f2bf(v[j]);
        vh[j] = h;
        vl[j] = f2bf(v[j] - bf2f(h));
      }
      int off = ((q >> 1) * 128 + r) * 8 + (q & 1) * 4;
      *reinterpret_cast<short4v*>(&Ah[off]) = vh;
      *reinterpret_cast<short4v*>(&Al[off]) = vl;
    }
    {
      int n = tid >> 1, half = tid & 1;
      size_t gb = (size_t)(n0 + n) * 1024 + k0 + half * 16;
      bf16x8 h0 = *reinterpret_cast<const bf16x8*>(&Bt_hi[gb]);
      bf16x8 h1 = *reinterpret_cast<const bf16x8*>(&Bt_hi[gb + 8]);
      bf16x8 l0 = *reinterpret_cast<const bf16x8*>(&Bt_lo[gb]);
      bf16x8 l1 = *reinterpret_cast<const bf16x8*>(&Bt_lo[gb + 8]);
      int kb = half * 2;
      *reinterpret_cast<bf16x8*>(&Bh[(kb * 128 + n) * 8]) = h0;
      *reinterpret_cast<bf16x8*>(&Bh[((kb + 1) * 128 + n) * 8]) = h1;
      *reinterpret_cast<bf16x8*>(&Bl[(kb * 128 + n) * 8]) = l0;
      *reinterpret_cast<bf16x8*>(&Bl[((kb + 1) * 128 + n) * 8]) = l1;
    }
    __syncthreads();

    bf16x8 a_h[4], a_l[4], b_h[4], b_l[4];
    #pragma unroll
    for (int mt = 0; mt < 4; ++mt) {
      int off = (lk * 128 + wm * 64 + mt * 16 + lr) * 8;
      a_h[mt] = *reinterpret_cast<const bf16x8*>(&Ah[off]);
      a_l[mt] = *reinterpret_cast<const bf16x8*>(&Al[off]);
    }
    #pragma unroll
    for (int nt = 0; nt < 4; ++nt) {
      int off = (lk * 128 + wn * 64 + nt * 16 + lr) * 8;
      b_h[nt] = *reinterpret_cast<const bf16x8*>(&Bh[off]);
      b_l[nt] = *reinterpret_cast<const bf16x8*>(&Bl[off]);
    }
    #pragma unroll
    for (int mt = 0; mt < 4; ++mt)
      #pragma unroll
      for (int nt = 0; nt < 4; ++nt) {
        acc[mt][nt] = __builtin_amdgcn_mfma_f32_16x16x32_bf16(a_h[mt], b_h[nt], acc[mt][nt], 0, 0, 0);
        acc[mt][nt] = __builtin_amdgcn_mfma_f32_16x16x32_bf16(a_h[mt], b_l[nt], acc[mt][nt], 0, 0, 0);
        acc[mt][nt] = __builtin_amdgcn_mfma_f32_16x16x32_bf16(a_l[mt], b_h[nt], acc[mt][nt], 0, 0, 0);
      }
  }
  #pragma unroll
  for (int nt = 0; nt < 4; ++nt) {
    int col = n0 + wn * 64 + nt * 16 + lr;
    float bv = bias[col];
    #pragma unroll
    for (int mt = 0; mt < 4; ++mt)
      #pragma unroll
      for (int r = 0; r < 4; ++r) {
        size_t row = m0 + wm * 64 + mt * 16 + lk * 4 + r;
        xp[row * 1024 + col] = acc[mt][nt][r] + bv;
      }
  }
}

// ---------------- pack init_state into h plane layout [g][kb128][row16][8] --------
__global__ __launch_bounds__(256) void k_init_h(
    const float* __restrict__ init, short* __restrict__ hhi, short* __restrict__ hlo)
{
  int i = blockIdx.x * 256 + threadIdx.x;   // 0..65535
  float v = init[i];
  int b = i >> 10, n = i & 1023;
  int g = b >> 4, row = b & 15, kb = n >> 3, e = n & 7;
  size_t off = ((size_t)(g * 128 + kb) * 16 + row) * 8 + e;
  short h = f2bf(v);
  hhi[off] = h;
  hlo[off] = f2bf(v - bf2f(h));
}

// ---------------- persistent recurrence: 512 steps, 4 groups x 32 WGs ------------
// R2-exact chassis (counter sync, tid0 poll + s_sleep, all-drain + barrier +
// single atomicAdd, 2-wave reduce/tanh tail, tid<128 pack, col-major W LDS,
// u64 MALL h planes). ONE change vs R2: wave = K-quarter computing BOTH
// N-tiles -> each h fragment loaded once per WG (MALL lines halved).
__global__ __launch_bounds__(256) void k_rnn(
    const float* __restrict__ xp,
    const short* __restrict__ whh_hi, const short* __restrict__ whh_lo,
    u64* __restrict__ hhi64, u64* __restrict__ hlo64,
    int* __restrict__ cnt, float* __restrict__ out)
{
  // W_hh^T slice [32 cols][1024 k] hi/lo, padded to 1032 (R2 layout)
  __shared__ __align__(16) short Wh[32 * 1032];
  __shared__ __align__(16) short Wl[32 * 1032];
  __shared__ __align__(16) float red[6 * 64 * 4];   // foreign partials, 6 slots
  __shared__ float stage[512];   // [row16][col32] (R2 layout)

  int bid = blockIdx.x;
  int g = bid & 3;               // batch-row group: rows g*16..+16
  int w = bid >> 2;              // 0..31: column slice
  int c0 = w * 32;
  int tid = threadIdx.x;
  int lane = tid & 63, wid = tid >> 6;
  int kh = wid;                  // wave = K-quarter (8 ksteps), both nt
  int lr = lane & 15, lk = lane >> 4;

  // fill W slice (once) — R2-exact col-major padded layout
  {
    int c = tid >> 3, seg = tid & 7;
    #pragma unroll
    for (int j = 0; j < 16; ++j) {
      int k = seg * 128 + j * 8;
      *reinterpret_cast<bf16x8*>(&Wh[c * 1032 + k]) =
          *reinterpret_cast<const bf16x8*>(&whh_hi[(size_t)(c0 + c) * 1024 + k]);
      *reinterpret_cast<bf16x8*>(&Wl[c * 1032 + k]) =
          *reinterpret_cast<const bf16x8*>(&whh_lo[(size_t)(c0 + c) * 1024 + k]);
    }
  }
  __syncthreads();

  int cbase = g * 512;
  for (int t = 0; t < TT; ++t) {
    // xp prefetch (independent of h) before the wait; waves 0,1 for nt=wid
    float xpv[4];
    if (wid < 2) {
      #pragma unroll
      for (int r = 0; r < 4; ++r) {
        int brow = g * 16 + lk * 4 + r;
        xpv[r] = xp[((size_t)t * 64 + brow) * 1024 + c0 + wid * 16 + lr];
      }
    }
    if (t > 0) {
      if (tid == 0) {
        while (__hip_atomic_load(&cnt[cbase + t - 1], __ATOMIC_RELAXED,
                                 __HIP_MEMORY_SCOPE_AGENT) < 32)
          __builtin_amdgcn_s_sleep(1);
      }
      __syncthreads();   // release: h(t) visible to everyone
    }
    const u64* hhq = hhi64 + (size_t)(t & 1) * 16384;
    const u64* hlq = hlo64 + (size_t)(t & 1) * 16384;
    f32x4 acc[2][2];
    #pragma unroll
    for (int nt = 0; nt < 2; ++nt)
      #pragma unroll
      for (int p = 0; p < 2; ++p) {
        acc[nt][p][0] = 0.f; acc[nt][p][1] = 0.f;
        acc[nt][p][2] = 0.f; acc[nt][p][3] = 0.f;
      }
    #pragma unroll
    for (int ks = 0; ks < 8; ++ks) {
      int kstep = kh * 8 + ks;
      int kb = kstep * 4 + lk;
      size_t ai = ((size_t)(g * 128 + kb) * 16 + lr) * 2;
      HU ua, ul;
      ua.q[0] = aload(hhq + ai); ua.q[1] = aload(hhq + ai + 1);
      ul.q[0] = aload(hlq + ai); ul.q[1] = aload(hlq + ai + 1);
      int p = ks & 1;
      #pragma unroll
      for (int nt = 0; nt < 2; ++nt) {
        int boff = (nt * 16 + lr) * 1032 + kstep * 32 + lk * 8;
        bf16x8 bh = *reinterpret_cast<const bf16x8*>(&Wh[boff]);
        bf16x8 bl = *reinterpret_cast<const bf16x8*>(&Wl[boff]);
        acc[nt][p] = __builtin_amdgcn_mfma_f32_16x16x32_bf16(ua.v, bh, acc[nt][p], 0, 0, 0);
        acc[nt][p] = __builtin_amdgcn_mfma_f32_16x16x32_bf16(ua.v, bl, acc[nt][p], 0, 0, 0);
        acc[nt][p] = __builtin_amdgcn_mfma_f32_16x16x32_bf16(ul.v, bh, acc[nt][p], 0, 0, 0);
      }
    }
    // publish foreign partials: nt0 from waves 1,2,3 -> slots 0,1,2;
    //                           nt1 from waves 0,2,3 -> slots 3,4,5.
    f32x4 s0, s1;
    #pragma unroll
    for (int r = 0; r < 4; ++r) {
      s0[r] = acc[0][0][r] + acc[0][1][r];
      s1[r] = acc[1][0][r] + acc[1][1][r];
    }
    if (wid != 0)
      *reinterpret_cast<f32x4*>(&red[((wid - 1) * 64 + lane) * 4]) = s0;
    if (wid != 1)
      *reinterpret_cast<f32x4*>(&red[((3 + (wid == 0 ? 0 : wid - 1)) * 64 + lane) * 4]) = s1;
    __syncthreads();                       // barrier1: red ready
    if (wid < 2) {                         // wave wid reduces nt=wid + tanh
      f32x4 s = (wid == 0) ? s0 : s1;
      int base = wid * 3;
      #pragma unroll
      for (int j = 0; j < 3; ++j) {
        f32x4 rv = *reinterpret_cast<const f32x4*>(&red[((base + j) * 64 + lane) * 4]);
        #pragma unroll
        for (int r = 0; r < 4; ++r) s[r] += rv[r];
      }
      #pragma unroll
      for (int r = 0; r < 4; ++r) {
        float v = s[r] + xpv[r];
        stage[(lk * 4 + r) * 32 + wid * 16 + lr] = tanhf(v);
      }
    }
    __syncthreads();                       // barrier2: stage ready
    // pack h_new -> MALL (hi/lo planes, u64 = 4 elems), 128 threads x 4 elems
    u64* nhq = hhi64 + (size_t)((t + 1) & 1) * 16384;
    u64* nlq = hlo64 + (size_t)((t + 1) & 1) * 16384;
    if (tid < 128) {
      int idx = tid * 4;
      int cb = idx >> 7, rem = idx & 127, row2 = rem >> 3, e = rem & 7;
      float v0 = stage[row2 * 32 + cb * 8 + e + 0];
      float v1 = stage[row2 * 32 + cb * 8 + e + 1];
      float v2 = stage[row2 * 32 + cb * 8 + e + 2];
      float v3 = stage[row2 * 32 + cb * 8 + e + 3];
      short h0 = f2bf(v0), h1 = f2bf(v1), h2 = f2bf(v2), h3 = f2bf(v3);
      short l0 = f2bf(v0 - bf2f(h0)), l1 = f2bf(v1 - bf2f(h1));
      short l2 = f2bf(v2 - bf2f(h2)), l3 = f2bf(v3 - bf2f(h3));
      u64 hw = (u64)(uint16_t)h0 | ((u64)(uint16_t)h1 << 16) |
               ((u64)(uint16_t)h2 << 32) | ((u64)(uint16_t)h3 << 48);
      u64 lw = (u64)(uint16_t)l0 | ((u64)(uint16_t)l1 << 16) |
               ((u64)(uint16_t)l2 << 32) | ((u64)(uint16_t)l3 << 48);
      size_t off = ((size_t)(g * 128 + w * 4 + cb) * 16 + row2) * 2 + (e >> 2);
      astore(nhq + off, hw);
      astore(nlq + off, lw);
      if (t == TT - 1) {
        size_t o = (size_t)(g * 16 + row2) * 1024 + c0 + cb * 8 + e;
        float4v ov; ov[0] = v0; ov[1] = v1; ov[2] = v2; ov[3] = v3;
        *reinterpret_cast<float4v*>(&out[o]) = ov;
        *reinterpret_cast<float4v*>(&out[65536 + o]) = ov;
      }
    }
    // release: drain each thread's sc1 stores to MALL, barrier, then signal.
    asm volatile("s_waitcnt vmcnt(0)" ::: "memory");
    __syncthreads();
    if (tid == 0)
      __hip_atomic_fetch_add(&cnt[cbase + t], 1, __ATOMIC_RELAXED,
                             __HIP_MEMORY_SCOPE_AGENT);
  }
}

extern "C" void kernel_launch(void* const* d_in, const int* in_sizes, int n_in,
                              void* d_out, int out_size, void* d_ws, size_t ws_size,
                              hipStream_t stream) {
  (void)in_sizes; (void)n_in; (void)out_size; (void)ws_size;
  const float* input      = (const float*)d_in[0];
  const float* init_state = (const float*)d_in[1];
  const float* W_ih       = (const float*)d_in[2];
  const float* W_hh       = (const float*)d_in[3];
  const float* bias       = (const float*)d_in[4];
  float* out = (float*)d_out;

  char* ws = (char*)d_ws;
  float* xp = (float*)ws;
  size_t off = (size_t)TT * BB * HH * 4;                 // 134.2 MB x_proj
  short* ih_hi = (short*)(ws + off); off += (size_t)DD * HH * 2;
  short* ih_lo = (short*)(ws + off); off += (size_t)DD * HH * 2;
  short* hh_hi = (short*)(ws + off); off += (size_t)HH * HH * 2;
  short* hh_lo = (short*)(ws + off); off += (size_t)HH * HH * 2;
  u64*   h_hi  = (u64*)(ws + off);   off += (size_t)2 * 16384 * 8;
  u64*   h_lo  = (u64*)(ws + off);   off += (size_t)2 * 16384 * 8;
  int*   cnt   = (int*)(ws + off);   off += (size_t)2048 * 4;

  hipMemsetAsync(cnt, 0, 2048 * 4, stream);
  k_wsplit<<<512, 256, 0, stream>>>(W_ih, W_hh, ih_hi, ih_lo, hh_hi, hh_lo);
  k_gemm_xp<<<2048, 256, 0, stream>>>(input, ih_hi, ih_lo, bias, xp);
  k_init_h<<<256, 256, 0, stream>>>(init_state, (short*)h_hi, (short*)h_lo);
  k_rnn<<<128, 256, 0, stream>>>(xp, hh_hi, hh_lo, h_hi, h_lo, cnt, out);
}